// Round 2
// baseline (116.652 us; speedup 1.0000x reference)
//
#include <hip/hip_runtime.h>
#include <math.h>

#define D 64
#define MAXM 20

__global__ void zero_kernel(int* __restrict__ p, int n) {
  int i = blockIdx.x * blockDim.x + threadIdx.x;
  if (i < n) p[i] = 0;
}

// One block (64 threads) per group: masked-mean embedding, dedup flags,
// unique count, and deg[u] scatter.
__global__ void group_init_kernel(const int* __restrict__ membership,
                                  const float* __restrict__ member_mask,
                                  const float* __restrict__ user_emb,
                                  float* __restrict__ emb0,
                                  int* __restrict__ uflag,
                                  int* __restrict__ ucnt,
                                  int* __restrict__ deg) {
  const int g = blockIdx.x;
  const int t = threadIdx.x;            // 0..63 = embedding dim
  __shared__ int   mem[MAXM];
  __shared__ float w[MAXM];
  __shared__ int   uf[MAXM];
  if (t < MAXM) {
    mem[t] = membership[g * MAXM + t];
    w[t]   = expf(member_mask[g * MAXM + t]);
  }
  __syncthreads();

  float acc = 0.f, wsum = 0.f;
#pragma unroll
  for (int m = 0; m < MAXM; ++m) {
    acc  += w[m] * user_emb[(long)mem[m] * D + t];
    wsum += w[m];
  }
  emb0[(long)g * D + t] = acc / wsum;

  if (t < MAXM) {
    int u = mem[t];
    int uniq = 1;
    for (int m = 0; m < t; ++m)
      if (mem[m] == u) uniq = 0;
    uf[t] = uniq;
    uflag[g * MAXM + t] = uniq;
    if (uniq) atomicAdd(&deg[u], 1);
  }
  __syncthreads();
  if (t == 0) {
    int c = 0;
    for (int m = 0; m < MAXM; ++m) c += uf[m];
    ucnt[g] = c;
  }
}

// Single-block exclusive prefix scan of deg[NU] -> off[NU+1]; cursor = off copy.
__global__ __launch_bounds__(1024) void scan_kernel(const int* __restrict__ deg,
                                                    int* __restrict__ off,
                                                    int* __restrict__ cursor,
                                                    int NU) {
  __shared__ int part[1024];
  const int t = threadIdx.x;
  const int chunk = (NU + 1023) >> 10;
  const int lo = t * chunk;
  const int hi = min(lo + chunk, NU);
  int s = 0;
  for (int i = lo; i < hi; ++i) s += deg[i];
  part[t] = s;
  __syncthreads();
  // inclusive Hillis-Steele scan over 1024 partials
  for (int o = 1; o < 1024; o <<= 1) {
    int v = (t >= o) ? part[t - o] : 0;
    __syncthreads();
    part[t] += v;
    __syncthreads();
  }
  int base = part[t] - s;  // exclusive prefix of this thread's chunk
  for (int i = lo; i < hi; ++i) {
    off[i] = base;
    cursor[i] = base;
    base += deg[i];
  }
  if (t == 1023) off[NU] = part[1023];
}

// inv[off[u] ..] = list of groups containing user u (unique slots only)
__global__ void invfill_kernel(const int* __restrict__ membership,
                               const int* __restrict__ uflag,
                               int* __restrict__ cursor,
                               int* __restrict__ inv, int total_slots) {
  int i = blockIdx.x * blockDim.x + threadIdx.x;
  if (i >= total_slots) return;
  if (uflag[i]) {
    int u = membership[i];
    int g = i / MAXM;
    int pos = atomicAdd(&cursor[u], 1);
    inv[pos] = g;
  }
}

// ng[g] = sum_{u in g uniq} sum_{g' in inv[u]} emb[g']  - ucnt[g]*emb[g]
// nm[g] = sum_{u in g uniq} (deg[u]-1)*U[u]   (computed when compute_nm, else read)
// emb_out = l2norm( [emb, ng+nm] @ Wk[k]^T + bk[k] )
__global__ void update_kernel(const int* __restrict__ membership,
                              const int* __restrict__ uflag,
                              const int* __restrict__ ucnt,
                              const int* __restrict__ off,
                              const int* __restrict__ inv,
                              const int* __restrict__ deg,
                              const float* __restrict__ user_emb,
                              float* __restrict__ nm, int compute_nm,
                              const float* __restrict__ Wk,
                              const float* __restrict__ bk,
                              int k,
                              const float* __restrict__ emb_in,
                              float* __restrict__ emb_out) {
  const int g = blockIdx.x;
  const int t = threadIdx.x;
  __shared__ int   mem[MAXM];
  __shared__ int   uf[MAXM];
  __shared__ float e[D];
  __shared__ float ms[D];
  if (t < MAXM) {
    mem[t] = membership[g * MAXM + t];
    uf[t]  = uflag[g * MAXM + t];
  }
  const float ein = emb_in[(long)g * D + t];
  e[t] = ein;
  __syncthreads();

  float ng = 0.f;
  float nmv = 0.f;
  if (compute_nm) {
    for (int m = 0; m < MAXM; ++m) {
      if (!uf[m]) continue;
      const int u = mem[m];
      nmv += (float)(deg[u] - 1) * user_emb[(long)u * D + t];
      const int p0 = off[u], p1 = off[u + 1];
      for (int p = p0; p < p1; ++p)
        ng += emb_in[(long)inv[p] * D + t];
    }
    nm[(long)g * D + t] = nmv;
  } else {
    nmv = nm[(long)g * D + t];
    for (int m = 0; m < MAXM; ++m) {
      if (!uf[m]) continue;
      const int u = mem[m];
      const int p0 = off[u], p1 = off[u + 1];
      for (int p = p0; p < p1; ++p)
        ng += emb_in[(long)inv[p] * D + t];
    }
  }
  ng -= (float)ucnt[g] * ein;
  ms[t] = ng + nmv;
  __syncthreads();

  const float* Wrow = Wk + ((long)k * D + t) * (2 * D);
  float o = bk[k * D + t];
#pragma unroll
  for (int j = 0; j < D; ++j)
    o += e[j] * Wrow[j] + ms[j] * Wrow[D + j];

  float ss = o * o;
#pragma unroll
  for (int sh = 32; sh; sh >>= 1) ss += __shfl_xor(ss, sh);
  const float invn = 1.f / fmaxf(sqrtf(ss), 1e-12f);
  emb_out[(long)g * D + t] = o * invn;
}

// One wave (64 lanes) per batch element: x = ge*ie, 16 shuffle-reduced dots,
// relu, 16->1 dot, sigmoid.
__global__ void final_kernel(const int* __restrict__ groups,
                             const int* __restrict__ items,
                             const float* __restrict__ emb,
                             const float* __restrict__ item_emb,
                             const float* __restrict__ p1w,
                             const float* __restrict__ p1b,
                             const float* __restrict__ p2w,
                             const float* __restrict__ p2b,
                             float* __restrict__ out, int B) {
  const int wave = (blockIdx.x * blockDim.x + threadIdx.x) >> 6;
  const int lane = threadIdx.x & 63;
  if (wave >= B) return;
  const int g  = groups[wave];
  const int it = items[wave];
  const float x = emb[(long)g * D + lane] * item_emb[(long)it * D + lane];
  float acc2 = p2b[0];
#pragma unroll
  for (int j = 0; j < 16; ++j) {
    float p = x * p1w[j * D + lane];
#pragma unroll
    for (int off = 32; off; off >>= 1) p += __shfl_xor(p, off);
    const float h = fmaxf(p + p1b[j], 0.f);
    acc2 += h * p2w[j];
  }
  if (lane == 0) out[wave] = 1.f / (1.f + expf(-acc2));
}

extern "C" void kernel_launch(void* const* d_in, const int* in_sizes, int n_in,
                              void* d_out, int out_size, void* d_ws, size_t ws_size,
                              hipStream_t stream) {
  const int*   groups      = (const int*)d_in[0];
  const int*   items       = (const int*)d_in[1];
  const int*   membership  = (const int*)d_in[2];
  const float* member_mask = (const float*)d_in[3];
  // d_in[4] hyper_graph: NOT needed (sparse identity via membership lists)
  const float* user_emb    = (const float*)d_in[5];
  const float* item_emb    = (const float*)d_in[6];
  const float* Wk          = (const float*)d_in[7];
  const float* bk          = (const float*)d_in[8];
  const float* p1w         = (const float*)d_in[9];
  const float* p1b         = (const float*)d_in[10];
  const float* p2w         = (const float*)d_in[11];
  const float* p2b         = (const float*)d_in[12];
  float* out = (float*)d_out;

  const int B  = in_sizes[0];
  const int G  = in_sizes[2] / MAXM;
  const int NU = in_sizes[5] / D;
  const int K  = in_sizes[7] / (D * 2 * D);
  const int TOT = G * MAXM;

  char* ws = (char*)d_ws;
  float* emb_a  = (float*)ws; ws += (size_t)G * D * 4;
  float* emb_b  = (float*)ws; ws += (size_t)G * D * 4;
  float* nm     = (float*)ws; ws += (size_t)G * D * 4;
  int*   deg    = (int*)ws;   ws += (size_t)NU * 4;
  int*   off    = (int*)ws;   ws += (size_t)(NU + 1) * 4;
  int*   cursor = (int*)ws;   ws += (size_t)NU * 4;
  int*   inv    = (int*)ws;   ws += (size_t)TOT * 4;
  int*   uflag  = (int*)ws;   ws += (size_t)TOT * 4;
  int*   ucnt   = (int*)ws;   ws += (size_t)G * 4;

  zero_kernel<<<(NU + 255) / 256, 256, 0, stream>>>(deg, NU);
  group_init_kernel<<<G, 64, 0, stream>>>(membership, member_mask, user_emb,
                                          emb_a, uflag, ucnt, deg);
  scan_kernel<<<1, 1024, 0, stream>>>(deg, off, cursor, NU);
  invfill_kernel<<<(TOT + 255) / 256, 256, 0, stream>>>(membership, uflag,
                                                        cursor, inv, TOT);

  float* cur = emb_a;
  float* nxt = emb_b;
  for (int k = 0; k < K; ++k) {
    update_kernel<<<G, 64, 0, stream>>>(membership, uflag, ucnt, off, inv, deg,
                                        user_emb, nm, (k == 0) ? 1 : 0,
                                        Wk, bk, k, cur, nxt);
    float* tmp = cur; cur = nxt; nxt = tmp;
  }

  final_kernel<<<(B * 64 + 255) / 256, 256, 0, stream>>>(
      groups, items, cur, item_emb, p1w, p1b, p2w, p2b, out, B);
}

// Round 3
// 75.890 us; speedup vs baseline: 1.5371x; 1.5371x over previous
//
#include <hip/hip_runtime.h>
#include <math.h>

#define D 64
#define MAXM 20

// Zero both scatter buffers (NU*D floats each) and deg[NU].
__global__ void zero_kernel(float4* __restrict__ s0, float4* __restrict__ s1,
                            int* __restrict__ deg, int n4, int nu) {
  const int i = blockIdx.x * blockDim.x + threadIdx.x;
  const float4 z = make_float4(0.f, 0.f, 0.f, 0.f);
  if (i < n4) { s0[i] = z; s1[i] = z; }
  if (i < nu) deg[i] = 0;
}

// Extra zeroer for K>2 generality (re-zero one s buffer).
__global__ void zero1_kernel(float4* __restrict__ s, int n4) {
  const int i = blockIdx.x * blockDim.x + threadIdx.x;
  if (i < n4) s[i] = make_float4(0.f, 0.f, 0.f, 0.f);
}

// One block (64 threads) per group: masked-mean embedding, dedup flags,
// unique count, deg atomics, AND scatter of emb0 into s0 (block-local data,
// so the scatter fuses here with no extra dispatch).
__global__ void init_scatter_kernel(const int* __restrict__ membership,
                                    const float* __restrict__ member_mask,
                                    const float* __restrict__ user_emb,
                                    float* __restrict__ emb0,
                                    int* __restrict__ uflag,
                                    int* __restrict__ ucnt,
                                    int* __restrict__ deg,
                                    float* __restrict__ s0) {
  const int g = blockIdx.x;
  const int t = threadIdx.x;  // 0..63 = embedding dim
  __shared__ int   mem[MAXM];
  __shared__ float w[MAXM];
  __shared__ int   uf[MAXM];
  if (t < MAXM) {
    mem[t] = membership[g * MAXM + t];
    w[t]   = expf(member_mask[g * MAXM + t]);
  }
  __syncthreads();

  float acc = 0.f, wsum = 0.f;
#pragma unroll
  for (int m = 0; m < MAXM; ++m) {
    acc  += w[m] * user_emb[(long)mem[m] * D + t];
    wsum += w[m];
  }
  const float e0 = acc / wsum;
  emb0[(long)g * D + t] = e0;

  if (t < MAXM) {
    const int u = mem[t];
    int uniq = 1;
    for (int m = 0; m < t; ++m)
      if (mem[m] == u) uniq = 0;
    uf[t] = uniq;
    uflag[g * MAXM + t] = uniq;
    if (uniq) atomicAdd(&deg[u], 1);
  }
  __syncthreads();

#pragma unroll
  for (int m = 0; m < MAXM; ++m)
    if (uf[m]) atomicAdd(&s0[(long)mem[m] * D + t], e0);

  if (t == 0) {
    int c = 0;
    for (int m = 0; m < MAXM; ++m) c += uf[m];
    ucnt[g] = c;
  }
}

// ng[g] = sum_{u in g uniq} s_in[u] - ucnt[g]*emb[g]
// nm[g] = sum_{u in g uniq} (deg[u]-1)*U[u]  (computed at k==0, reread after)
// emb_out = l2norm([emb, ng+nm] @ Wk[k]^T + bk[k]);
// then (if s_out) scatter emb_out into s_out for the next iteration.
__global__ void update_kernel(const int* __restrict__ membership,
                              const int* __restrict__ uflag,
                              const int* __restrict__ ucnt,
                              const int* __restrict__ deg,
                              const float* __restrict__ user_emb,
                              const float* __restrict__ s_in,
                              float* __restrict__ nm, int compute_nm,
                              const float* __restrict__ Wk,
                              const float* __restrict__ bk,
                              int k,
                              const float* __restrict__ emb_in,
                              float* __restrict__ emb_out,
                              float* __restrict__ s_out) {
  const int g = blockIdx.x;
  const int t = threadIdx.x;
  __shared__ int   mem[MAXM];
  __shared__ int   uf[MAXM];
  __shared__ float e[D];
  __shared__ float ms[D];
  if (t < MAXM) {
    mem[t] = membership[g * MAXM + t];
    uf[t]  = uflag[g * MAXM + t];
  }
  const float ein = emb_in[(long)g * D + t];
  e[t] = ein;
  __syncthreads();

  float ng = 0.f, nmv = 0.f;
  if (compute_nm) {
#pragma unroll
    for (int m = 0; m < MAXM; ++m) {
      if (!uf[m]) continue;
      const int u = mem[m];
      ng  += s_in[(long)u * D + t];
      nmv += (float)(deg[u] - 1) * user_emb[(long)u * D + t];
    }
    nm[(long)g * D + t] = nmv;
  } else {
    nmv = nm[(long)g * D + t];
#pragma unroll
    for (int m = 0; m < MAXM; ++m) {
      if (!uf[m]) continue;
      ng += s_in[(long)mem[m] * D + t];
    }
  }
  ng -= (float)ucnt[g] * ein;
  ms[t] = ng + nmv;
  __syncthreads();

  const float* Wrow = Wk + ((long)k * D + t) * (2 * D);
  float o = bk[k * D + t];
#pragma unroll
  for (int j = 0; j < D; ++j)
    o += e[j] * Wrow[j] + ms[j] * Wrow[D + j];

  float ss = o * o;
#pragma unroll
  for (int sh = 32; sh; sh >>= 1) ss += __shfl_xor(ss, sh);
  o *= 1.f / fmaxf(sqrtf(ss), 1e-12f);
  emb_out[(long)g * D + t] = o;

  if (s_out) {
#pragma unroll
    for (int m = 0; m < MAXM; ++m)
      if (uf[m]) atomicAdd(&s_out[(long)mem[m] * D + t], o);
  }
}

// One wave per batch element: x = ge*ie, 16 shuffle-reduced dots, relu,
// 16->1 dot, sigmoid.
__global__ void final_kernel(const int* __restrict__ groups,
                             const int* __restrict__ items,
                             const float* __restrict__ emb,
                             const float* __restrict__ item_emb,
                             const float* __restrict__ p1w,
                             const float* __restrict__ p1b,
                             const float* __restrict__ p2w,
                             const float* __restrict__ p2b,
                             float* __restrict__ out, int B) {
  const int wave = (blockIdx.x * blockDim.x + threadIdx.x) >> 6;
  const int lane = threadIdx.x & 63;
  if (wave >= B) return;
  const int g  = groups[wave];
  const int it = items[wave];
  const float x = emb[(long)g * D + lane] * item_emb[(long)it * D + lane];
  float acc2 = p2b[0];
#pragma unroll
  for (int j = 0; j < 16; ++j) {
    float p = x * p1w[j * D + lane];
#pragma unroll
    for (int off = 32; off; off >>= 1) p += __shfl_xor(p, off);
    const float h = fmaxf(p + p1b[j], 0.f);
    acc2 += h * p2w[j];
  }
  if (lane == 0) out[wave] = 1.f / (1.f + expf(-acc2));
}

extern "C" void kernel_launch(void* const* d_in, const int* in_sizes, int n_in,
                              void* d_out, int out_size, void* d_ws, size_t ws_size,
                              hipStream_t stream) {
  const int*   groups      = (const int*)d_in[0];
  const int*   items       = (const int*)d_in[1];
  const int*   membership  = (const int*)d_in[2];
  const float* member_mask = (const float*)d_in[3];
  // d_in[4] hyper_graph: not needed (binary incidence == membership lists)
  const float* user_emb    = (const float*)d_in[5];
  const float* item_emb    = (const float*)d_in[6];
  const float* Wk          = (const float*)d_in[7];
  const float* bk          = (const float*)d_in[8];
  const float* p1w         = (const float*)d_in[9];
  const float* p1b         = (const float*)d_in[10];
  const float* p2w         = (const float*)d_in[11];
  const float* p2b         = (const float*)d_in[12];
  float* out = (float*)d_out;

  const int B  = in_sizes[0];
  const int G  = in_sizes[2] / MAXM;
  const int NU = in_sizes[5] / D;
  const int K  = in_sizes[7] / (D * 2 * D);
  const int TOT = G * MAXM;

  char* ws = (char*)d_ws;
  float* emb_a = (float*)ws; ws += (size_t)G * D * 4;
  float* emb_b = (float*)ws; ws += (size_t)G * D * 4;
  float* nm    = (float*)ws; ws += (size_t)G * D * 4;
  float* s0    = (float*)ws; ws += (size_t)NU * D * 4;
  float* s1    = (float*)ws; ws += (size_t)NU * D * 4;
  int*   deg   = (int*)ws;   ws += (size_t)NU * 4;
  int*   uflag = (int*)ws;   ws += (size_t)TOT * 4;
  int*   ucnt  = (int*)ws;   ws += (size_t)G * 4;

  const int n4 = NU * D / 4;
  zero_kernel<<<(n4 + 255) / 256, 256, 0, stream>>>(
      (float4*)s0, (float4*)s1, deg, n4, NU);

  init_scatter_kernel<<<G, 64, 0, stream>>>(membership, member_mask, user_emb,
                                            emb_a, uflag, ucnt, deg, s0);

  float* cur = emb_a;
  float* nxt = emb_b;
  float* sin_ = s0;
  float* sout = s1;
  for (int k = 0; k < K; ++k) {
    if (k >= 2) {  // re-zero the buffer we are about to scatter into
      zero1_kernel<<<(n4 + 255) / 256, 256, 0, stream>>>((float4*)sout, n4);
    }
    update_kernel<<<G, 64, 0, stream>>>(
        membership, uflag, ucnt, deg, user_emb, sin_, nm, (k == 0) ? 1 : 0,
        Wk, bk, k, cur, nxt, (k + 1 < K) ? sout : nullptr);
    float* tmp = cur; cur = nxt; nxt = tmp;
    float* ts = sin_; sin_ = sout; sout = ts;
  }

  final_kernel<<<(B * 64 + 255) / 256, 256, 0, stream>>>(
      groups, items, cur, item_emb, p1w, p1b, p2w, p2b, out, B);
}